// Round 13
// baseline (1300.140 us; speedup 1.0000x reference)
//
#include <hip/hip_runtime.h>
#include <hip/hip_bf16.h>
#include <cstdint>
#include <cstddef>

#define DM 2048
#define DG 512
#define NBATCH 4
#define NT 4096
#define NM (NBATCH*NT)     // 16384 rows
#define KC (2*DM)          // 4096 concat-K (i8 elems = bytes)
#define LN_EPS 1e-5f
#define NTILES (KC/128)    // 32 K-tiles of BK=128 i8
#define SCL_A 16.0f
#define SCL_B 8192.0f
#define DESCALE (1.0f/131072.0f)
#define INV_SCL_A 0.0625f

typedef __bf16 bf16;
typedef bf16 bf16x8 __attribute__((ext_vector_type(8)));
typedef float f32x4 __attribute__((ext_vector_type(4)));
typedef int   i32x4 __attribute__((ext_vector_type(4)));
typedef char  i8x8  __attribute__((ext_vector_type(8)));
typedef unsigned char u8x8 __attribute__((ext_vector_type(8)));

#define AS1 __attribute__((address_space(1)))
#define AS3 __attribute__((address_space(3)))

__device__ __forceinline__ char q8(float x, float s) {
    int v = (int)rintf(x * s);
    v = v > 127 ? 127 : (v < -127 ? -127 : v);
    return (char)v;
}

__device__ __forceinline__ void block_reduce_2(float& s, float& s2) {
#pragma unroll
    for (int off = 32; off; off >>= 1) {
        s  += __shfl_down(s, off);
        s2 += __shfl_down(s2, off);
    }
    __shared__ float sm[8];
    const int wid = threadIdx.x >> 6, lane = threadIdx.x & 63;
    if (lane == 0) { sm[wid] = s; sm[4 + wid] = s2; }
    __syncthreads();
    s  = sm[0] + sm[1] + sm[2] + sm[3];
    s2 = sm[4] + sm[5] + sm[6] + sm[7];
}

// ---------- fused: blocks [0,512) = GEMV proj; blocks [512,4608) = w_gate->i8 ----------
__global__ void k_pack_dot1(const float* __restrict__ wg, int8_t* __restrict__ wqb,
                            const float* __restrict__ X, const float* __restrict__ W,
                            const float* __restrict__ bias, float* __restrict__ out) {
    if (blockIdx.x >= 512) {
        const int i = (blockIdx.x - 512) * 256 + threadIdx.x;
        const f32x4* s = (const f32x4*)wg + (size_t)i * 2;
        f32x4 a = s[0], b = s[1];
        i8x8 o;
#pragma unroll
        for (int q = 0; q < 4; q++) { o[q] = q8(a[q], SCL_B); o[4+q] = q8(b[q], SCL_B); }
        *((i8x8*)wqb + i) = o;
        return;
    }
    const int lane = threadIdx.x & 63;
    const int wid  = threadIdx.x >> 6;
    const int j = blockIdx.x * 4 + wid;
    const f32x4* Wr = (const f32x4*)(W + (size_t)j * DG);
    float acc[NBATCH] = {0.f, 0.f, 0.f, 0.f};
    constexpr int C = DG / 4 / 64;
#pragma unroll
    for (int i = 0; i < C; i++) {
        f32x4 wv = Wr[lane + 64 * i];
#pragma unroll
        for (int b = 0; b < NBATCH; b++) {
            f32x4 xv = ((const f32x4*)(X + (size_t)b * DG))[lane + 64 * i];
            acc[b] += wv[0]*xv[0] + wv[1]*xv[1] + wv[2]*xv[2] + wv[3]*xv[3];
        }
    }
#pragma unroll
    for (int off = 32; off; off >>= 1)
#pragma unroll
        for (int b = 0; b < NBATCH; b++) acc[b] += __shfl_down(acc[b], off);
    if (lane == 0) {
        const float bb = bias[j];
#pragma unroll
        for (int b = 0; b < NBATCH; b++) out[(size_t)b * DM + j] = acc[b] + bb;
    }
}

template<int K>
__global__ void k_dot(const float* __restrict__ X, const float* __restrict__ W,
                      const float* __restrict__ bias, float* __restrict__ out) {
    const int lane = threadIdx.x & 63;
    const int wid  = threadIdx.x >> 6;
    const int j = blockIdx.x * 4 + wid;
    const f32x4* Wr = (const f32x4*)(W + (size_t)j * K);
    float acc[NBATCH] = {0.f, 0.f, 0.f, 0.f};
    constexpr int C = K / 4 / 64;
#pragma unroll
    for (int i = 0; i < C; i++) {
        f32x4 wv = Wr[lane + 64 * i];
#pragma unroll
        for (int b = 0; b < NBATCH; b++) {
            f32x4 xv = ((const f32x4*)(X + (size_t)b * K))[lane + 64 * i];
            acc[b] += wv[0]*xv[0] + wv[1]*xv[1] + wv[2]*xv[2] + wv[3]*xv[3];
        }
    }
#pragma unroll
    for (int off = 32; off; off >>= 1)
#pragma unroll
        for (int b = 0; b < NBATCH; b++) acc[b] += __shfl_down(acc[b], off);
    if (lane == 0) {
        const float bb = bias[j];
#pragma unroll
        for (int b = 0; b < NBATCH; b++) out[(size_t)b * DM + j] = acc[b] + bb;
    }
}

__global__ void k_ln_small(const float* __restrict__ in, const float* __restrict__ g,
                           const float* __restrict__ bt, float* __restrict__ out) {
    const int row = blockIdx.x;
    const int tid = threadIdx.x;
    const f32x4* ir = (const f32x4*)(in + (size_t)row * DM);
    f32x4 v0 = ir[tid], v1 = ir[tid + 256];
    float s  = v0[0]+v0[1]+v0[2]+v0[3] + v1[0]+v1[1]+v1[2]+v1[3];
    float s2 = v0[0]*v0[0]+v0[1]*v0[1]+v0[2]*v0[2]+v0[3]*v0[3]
             + v1[0]*v1[0]+v1[1]*v1[1]+v1[2]*v1[2]+v1[3]*v1[3];
    block_reduce_2(s, s2);
    const float mu = s * (1.0f / DM);
    const float r  = rsqrtf(s2 * (1.0f / DM) - mu * mu + LN_EPS);
    f32x4 g0 = ((const f32x4*)g)[tid],  g1v = ((const f32x4*)g)[tid + 256];
    f32x4 b0 = ((const f32x4*)bt)[tid], b1v = ((const f32x4*)bt)[tid + 256];
    f32x4 o0 = (v0 - mu) * r * g0 + b0;
    f32x4 o1 = (v1 - mu) * r * g1v + b1v;
    f32x4* orow = (f32x4*)(out + (size_t)row * DM);
    orow[tid] = o0; orow[tid + 256] = o1;
}

__global__ void k_stats_pack(const float* __restrict__ h, const float* __restrict__ attnv,
                             const float* __restrict__ g2, const float* __restrict__ b2,
                             int8_t* __restrict__ Aq,
                             float* __restrict__ muA, float* __restrict__ rA) {
    const int m = blockIdx.x;
    const int b = m >> 12;
    const int tid = threadIdx.x;
    const f32x4* hr = (const f32x4*)(h + (size_t)m * DM);
    const f32x4* ar = (const f32x4*)(attnv + (size_t)b * DM);
    f32x4 h0 = hr[2*tid], h1 = hr[2*tid + 1];
    f32x4 a0 = ar[2*tid], a1 = ar[2*tid + 1];
    f32x4 x0 = h0 + a0, x1 = h1 + a1;
    float s  = x0[0]+x0[1]+x0[2]+x0[3] + x1[0]+x1[1]+x1[2]+x1[3];
    float s2 = x0[0]*x0[0]+x0[1]*x0[1]+x0[2]*x0[2]+x0[3]*x0[3]
             + x1[0]*x1[0]+x1[1]*x1[1]+x1[2]*x1[2]+x1[3]*x1[3];
    block_reduce_2(s, s2);
    const float mu = s * (1.0f / DM);
    const float r  = rsqrtf(s2 * (1.0f / DM) - mu * mu + LN_EPS);
    if (tid == 0) { muA[m] = mu; rA[m] = r; }
    f32x4 gg0 = ((const f32x4*)g2)[2*tid], gg1 = ((const f32x4*)g2)[2*tid + 1];
    f32x4 bb0 = ((const f32x4*)b2)[2*tid], bb1 = ((const f32x4*)b2)[2*tid + 1];
    f32x4 ao0 = (x0 - mu) * r * gg0 + bb0;
    f32x4 ao1 = (x1 - mu) * r * gg1 + bb1;
    i8x8 qh, qa;
#pragma unroll
    for (int q = 0; q < 4; q++) {
        qh[q] = q8(h0[q], SCL_A);  qh[4+q] = q8(h1[q], SCL_A);
        qa[q] = q8(ao0[q], SCL_A); qa[4+q] = q8(ao1[q], SCL_A);
    }
    *(i8x8*)(Aq + (size_t)m * KC + 8*tid) = qh;
    *(i8x8*)(Aq + (size_t)m * KC + DM + 8*tid) = qa;
}

// ---------- 256x256 i8 GEMM v12: BK=128 (r7 proven layout), SINGLE buffer = 64KB LDS ----------
// -> 2 blocks/CU co-resident, mutually out of phase: block B's MFMA covers block A's
// stage/drain stall (m114 mechanism). Per tile: stage 8 -> VM(0)+BAR -> r7 lgkm-ladder
// compute -> BAR. 128B rows + r7 XOR swizzle (measured 0 conflicts). Rule from r10-12:
// b128 LDS tiles need >=128B rows — 64B rows cost an unavoidable +4cyc/read.
#define MF(a,b,c) __builtin_amdgcn_mfma_i32_16x16x64_i8(a,b,c,0,0,0)
#define SCHED0() __builtin_amdgcn_sched_barrier(0)
#define BAR()  { SCHED0(); asm volatile("s_barrier" ::: "memory"); SCHED0(); }
#define VM(n)  { asm volatile("s_waitcnt vmcnt(" #n ")" ::: "memory"); SCHED0(); }
#define LGKM(n) { asm volatile("s_waitcnt lgkmcnt(" #n ")" ::: "memory"); SCHED0(); }

__global__ __launch_bounds__(512, 4) void k_gemm256(const int8_t* __restrict__ A, const int8_t* __restrict__ Bw,
                                                    const float* __restrict__ bgate, uint8_t* __restrict__ gq) {
    __shared__ __align__(128) char smem[65536];   // single buf: [A 32KB | B 32KB]
    const int tid  = threadIdx.x;
    const int lane = tid & 63;
    const int wid  = tid >> 6;
    const int wm   = wid >> 2, wn = wid & 3;

    // bijective XCD swizzle: 512 blocks, 8 XCDs
    const int swz = (blockIdx.x & 7) * 64 + (blockIdx.x >> 3);
    const int bm = (swz >> 3) << 8;
    const int bn = (swz & 7) << 8;

    // staging: inverse-swizzled global source (r7 scheme), linear LDS dest
    const int r_local = tid >> 3;                 // row within a 64-row round
    const int sc = (tid & 7) ^ (r_local & 7);     // swizzled 16B chunk in 128B row
    const int8_t* Abase = A  + (size_t)(bm + r_local) * KC + sc*16;
    const int8_t* Bbase = Bw + (size_t)(bn + r_local) * KC + sc*16;
    const int ldsW = wid << 10;

#define STAGEA(rnd, kt) __builtin_amdgcn_global_load_lds( \
        (const AS1 void*)(Abase + (size_t)(rnd)*64*KC + (kt)*128), \
        (AS3 void*)(smem + (rnd)*8192 + ldsW), 16, 0, 0)
#define STAGEB(rnd, kt) __builtin_amdgcn_global_load_lds( \
        (const AS1 void*)(Bbase + (size_t)(rnd)*64*KC + (kt)*128), \
        (AS3 void*)(smem + 32768 + (rnd)*8192 + ldsW), 16, 0, 0)

    // fragment read byte offsets (r7 swizzle); rows are 128B
    const int co0 = ((lane >> 4) ^ (lane & 7)) << 4;         // ks=0: chunks 0-3
    const int co1 = ((4 + (lane >> 4)) ^ (lane & 7)) << 4;   // ks=1: chunks 4-7
    const int arowb = (wm*128 + (lane & 15)) * 128;
    const int browb = (wn*64  + (lane & 15)) * 128;

#define AFRG(m, ks) (*(const i32x4*)(smem + arowb + (m)*2048 + ((ks) ? co1 : co0)))
#define BFRG(n, ks) (*(const i32x4*)(smem + 32768 + browb + (n)*2048 + ((ks) ? co1 : co0)))

    i32x4 acc[8][4] = {};
    i32x4 aLo[4][2], aHi[4][2], b01[2][2], b23[2][2];

#define LOAD_ALO() { _Pragma("unroll") for (int i = 0; i < 4; i++) { aLo[i][0] = AFRG(i,0);   aLo[i][1] = AFRG(i,1);   } }
#define LOAD_AHI() { _Pragma("unroll") for (int i = 0; i < 4; i++) { aHi[i][0] = AFRG(4+i,0); aHi[i][1] = AFRG(4+i,1); } }
#define LOAD_B01() { _Pragma("unroll") for (int j = 0; j < 2; j++) { b01[j][0] = BFRG(j,0);   b01[j][1] = BFRG(j,1);   } }
#define LOAD_B23() { _Pragma("unroll") for (int j = 0; j < 2; j++) { b23[j][0] = BFRG(2+j,0); b23[j][1] = BFRG(2+j,1); } }

#define MMQ(MOFF, AF, BF, NOFF) { _Pragma("unroll") for (int i = 0; i < 4; i++) \
        _Pragma("unroll") for (int j = 0; j < 2; j++) { \
            acc[(MOFF)+i][(NOFF)+j] = MF(AF[i][0], BF[j][0], acc[(MOFF)+i][(NOFF)+j]); \
            acc[(MOFF)+i][(NOFF)+j] = MF(AF[i][1], BF[j][1], acc[(MOFF)+i][(NOFF)+j]); } }

    for (int T = 0; T < NTILES; ++T) {
        // stage tile T (buffer free: all waves passed the end-BAR of T-1)
        STAGEB(0, T); STAGEB(1, T); STAGEB(2, T); STAGEB(3, T);
        STAGEA(0, T); STAGEA(1, T); STAGEA(2, T); STAGEA(3, T);
        VM(0);
        BAR();
        // compute (r7 ladder): 16 reads, LGKM(4), Q0; 8 reads ahead, LGKM(8), Q1; LGKM(0) Q2; Q3
        LOAD_ALO(); LOAD_B01(); LOAD_B23(); SCHED0();
        LGKM(4);
        __builtin_amdgcn_s_setprio(1);
        MMQ(0, aLo, b01, 0);
        __builtin_amdgcn_s_setprio(0); SCHED0();
        LOAD_AHI(); SCHED0();
        LGKM(8);
        __builtin_amdgcn_s_setprio(1);
        MMQ(0, aLo, b23, 2);
        __builtin_amdgcn_s_setprio(0); SCHED0();
        LGKM(0);
        __builtin_amdgcn_s_setprio(1);
        MMQ(4, aHi, b23, 2);
        __builtin_amdgcn_s_setprio(0); SCHED0();
        __builtin_amdgcn_s_setprio(1);
        MMQ(4, aHi, b01, 0);
        __builtin_amdgcn_s_setprio(0); SCHED0();
        BAR();   // all waves done reading tile T -> safe to overwrite
    }

    // ---- epilogue: gate = sigmoid(acc*DESCALE + bias) -> u8
#pragma unroll
    for (int n = 0; n < 4; n++) {
        const int col = bn + wn*64 + n*16 + (lane & 15);
        const float bg = bgate[col];
#pragma unroll
        for (int m = 0; m < 8; m++) {
            const int row = bm + wm*128 + m*16 + ((lane >> 4) << 2);
#pragma unroll
            for (int r = 0; r < 4; r++) {
                const float z = (float)acc[m][n][r] * DESCALE + bg;
                const float gate = 1.0f / (1.0f + __expf(-z));
                gq[(size_t)(row + r) * DM + col] = (uint8_t)(int)rintf(gate * 255.0f);
            }
        }
    }
}

// ---------- epilogue: blend with u8 gate + i8 h (from Aq), LN3 per row ----------
__global__ void k_epilogue(const int8_t* __restrict__ Aq, const uint8_t* __restrict__ gq,
                           const float* __restrict__ attnv, const float* __restrict__ muA,
                           const float* __restrict__ rA,
                           const float* __restrict__ g2, const float* __restrict__ b2,
                           const float* __restrict__ g3, const float* __restrict__ b3,
                           float* __restrict__ out) {
    const int m = blockIdx.x;
    const int b = m >> 12;
    const int tid = threadIdx.x;
    i8x8 qh = *(const i8x8*)(Aq + (size_t)m * KC + 8*tid);
    f32x4 h0, h1;
#pragma unroll
    for (int q = 0; q < 4; q++) { h0[q] = (float)qh[q] * INV_SCL_A; h1[q] = (float)qh[4+q] * INV_SCL_A; }
    const f32x4* ar = (const f32x4*)(attnv + (size_t)b * DM);
    f32x4 a0 = ar[2*tid], a1 = ar[2*tid + 1];
    const float mu = muA[m];
    const float r  = rA[m];
    f32x4 gg0 = ((const f32x4*)g2)[2*tid], gg1 = ((const f32x4*)g2)[2*tid + 1];
    f32x4 bb0 = ((const f32x4*)b2)[2*tid], bb1 = ((const f32x4*)b2)[2*tid + 1];
    f32x4 ao0 = (h0 + a0 - mu) * r * gg0 + bb0;
    f32x4 ao1 = (h1 + a1 - mu) * r * gg1 + bb1;
    u8x8 qv = *(const u8x8*)(gq + (size_t)m * DM + 8*tid);
    f32x4 gt0, gt1;
#pragma unroll
    for (int q = 0; q < 4; q++) {
        gt0[q] = (float)qv[q]   * (1.0f / 255.0f);
        gt1[q] = (float)qv[4+q] * (1.0f / 255.0f);
    }
    f32x4 f0 = h0 + gt0 * (ao0 - h0);
    f32x4 f1 = h1 + gt1 * (ao1 - h1);
    float s  = f0[0]+f0[1]+f0[2]+f0[3] + f1[0]+f1[1]+f1[2]+f1[3];
    float s2 = f0[0]*f0[0]+f0[1]*f0[1]+f0[2]*f0[2]+f0[3]*f0[3]
             + f1[0]*f1[0]+f1[1]*f1[1]+f1[2]*f1[2]+f1[3]*f1[3];
    block_reduce_2(s, s2);
    const float mu3 = s * (1.0f / DM);
    const float r3  = rsqrtf(s2 * (1.0f / DM) - mu3 * mu3 + LN_EPS);
    f32x4 g30 = ((const f32x4*)g3)[2*tid], g31 = ((const f32x4*)g3)[2*tid + 1];
    f32x4 b30 = ((const f32x4*)b3)[2*tid], b31 = ((const f32x4*)b3)[2*tid + 1];
    f32x4 o0 = (f0 - mu3) * r3 * g30 + b30;
    f32x4 o1 = (f1 - mu3) * r3 * g31 + b31;
    f32x4* orow = (f32x4*)(out + (size_t)m * DM);
    orow[2*tid] = o0; orow[2*tid + 1] = o1;
}

extern "C" void kernel_launch(void* const* d_in, const int* in_sizes, int n_in,
                              void* d_out, int out_size, void* d_ws, size_t ws_size,
                              hipStream_t stream) {
    const float* h_llm    = (const float*)d_in[0];
    const float* h_change = (const float*)d_in[1];
    const float* w_proj   = (const float*)d_in[2];
    const float* b_proj   = (const float*)d_in[3];
    const float* g1       = (const float*)d_in[4];
    const float* b1       = (const float*)d_in[5];
    const float* w_v      = (const float*)d_in[6];
    const float* b_v      = (const float*)d_in[7];
    const float* w_o      = (const float*)d_in[8];
    const float* b_o      = (const float*)d_in[9];
    const float* g2       = (const float*)d_in[10];
    const float* b2       = (const float*)d_in[11];
    const float* w_gate   = (const float*)d_in[12];
    const float* b_gate   = (const float*)d_in[13];
    const float* g3       = (const float*)d_in[14];
    const float* b3       = (const float*)d_in[15];
    float* out = (float*)d_out;

    char* ws = (char*)d_ws;
    int8_t* Aq  = (int8_t*)ws; ws += (size_t)NM * KC;          // 67.1 MB
    int8_t* wqb = (int8_t*)ws; ws += (size_t)DM * KC;          // 8.4 MB
    uint8_t* gq = (uint8_t*)ws; ws += (size_t)NM * DM;         // 33.5 MB
    float* muA = (float*)ws;  ws += (size_t)NM * 4;
    float* rA  = (float*)ws;  ws += (size_t)NM * 4;
    float* raw1 = (float*)ws; ws += (size_t)NBATCH * DM * 4;
    float* hc   = (float*)ws; ws += (size_t)NBATCH * DM * 4;
    float* raw2 = (float*)ws; ws += (size_t)NBATCH * DM * 4;
    float* attnv= (float*)ws; ws += (size_t)NBATCH * DM * 4;

    k_pack_dot1<<<4608, 256, 0, stream>>>(w_gate, wqb, h_change, w_proj, b_proj, raw1);
    k_ln_small<<<NBATCH, 256, 0, stream>>>(raw1, g1, b1, hc);
    k_dot<DM><<<DM / 4, 256, 0, stream>>>(hc, w_v, b_v, raw2);
    k_dot<DM><<<DM / 4, 256, 0, stream>>>(raw2, w_o, b_o, attnv);
    k_stats_pack<<<NM, 256, 0, stream>>>(h_llm, attnv, g2, b2, Aq, muA, rA);
    k_gemm256<<<512, 512, 0, stream>>>(Aq, wqb, b_gate, gq);
    k_epilogue<<<NM, 256, 0, stream>>>(Aq, gq, attnv, muA, rA, g2, b2, g3, b3, out);
}

// Round 14
// 270.631 us; speedup vs baseline: 4.8041x; 4.8041x over previous
//
#include <hip/hip_runtime.h>
#include <hip/hip_bf16.h>
#include <cstdint>
#include <cstddef>

#define DM 2048
#define DG 512
#define NBATCH 4
#define NT 4096
#define NM (NBATCH*NT)     // 16384 rows
#define KC (2*DM)          // 4096 concat-K (i8 elems = bytes)
#define LN_EPS 1e-5f
#define NTILES (KC/128)    // 32 K-tiles of BK=128 i8
#define SCL_A 16.0f
#define SCL_B 8192.0f
#define DESCALE (1.0f/131072.0f)
#define INV_SCL_A 0.0625f

typedef __bf16 bf16;
typedef bf16 bf16x8 __attribute__((ext_vector_type(8)));
typedef float f32x4 __attribute__((ext_vector_type(4)));
typedef int   i32x4 __attribute__((ext_vector_type(4)));
typedef char  i8x8  __attribute__((ext_vector_type(8)));
typedef unsigned char u8x8 __attribute__((ext_vector_type(8)));

#define AS1 __attribute__((address_space(1)))
#define AS3 __attribute__((address_space(3)))

__device__ __forceinline__ char q8(float x, float s) {
    int v = (int)rintf(x * s);
    v = v > 127 ? 127 : (v < -127 ? -127 : v);
    return (char)v;
}

__device__ __forceinline__ void block_reduce_2(float& s, float& s2) {
#pragma unroll
    for (int off = 32; off; off >>= 1) {
        s  += __shfl_down(s, off);
        s2 += __shfl_down(s2, off);
    }
    __shared__ float sm[8];
    const int wid = threadIdx.x >> 6, lane = threadIdx.x & 63;
    if (lane == 0) { sm[wid] = s; sm[4 + wid] = s2; }
    __syncthreads();
    s  = sm[0] + sm[1] + sm[2] + sm[3];
    s2 = sm[4] + sm[5] + sm[6] + sm[7];
}

// ---------- fused: blocks [0,512) = GEMV proj; blocks [512,4608) = w_gate->i8 ----------
__global__ void k_pack_dot1(const float* __restrict__ wg, int8_t* __restrict__ wqb,
                            const float* __restrict__ X, const float* __restrict__ W,
                            const float* __restrict__ bias, float* __restrict__ out) {
    if (blockIdx.x >= 512) {
        const int i = (blockIdx.x - 512) * 256 + threadIdx.x;
        const f32x4* s = (const f32x4*)wg + (size_t)i * 2;
        f32x4 a = s[0], b = s[1];
        i8x8 o;
#pragma unroll
        for (int q = 0; q < 4; q++) { o[q] = q8(a[q], SCL_B); o[4+q] = q8(b[q], SCL_B); }
        *((i8x8*)wqb + i) = o;
        return;
    }
    const int lane = threadIdx.x & 63;
    const int wid  = threadIdx.x >> 6;
    const int j = blockIdx.x * 4 + wid;
    const f32x4* Wr = (const f32x4*)(W + (size_t)j * DG);
    float acc[NBATCH] = {0.f, 0.f, 0.f, 0.f};
    constexpr int C = DG / 4 / 64;
#pragma unroll
    for (int i = 0; i < C; i++) {
        f32x4 wv = Wr[lane + 64 * i];
#pragma unroll
        for (int b = 0; b < NBATCH; b++) {
            f32x4 xv = ((const f32x4*)(X + (size_t)b * DG))[lane + 64 * i];
            acc[b] += wv[0]*xv[0] + wv[1]*xv[1] + wv[2]*xv[2] + wv[3]*xv[3];
        }
    }
#pragma unroll
    for (int off = 32; off; off >>= 1)
#pragma unroll
        for (int b = 0; b < NBATCH; b++) acc[b] += __shfl_down(acc[b], off);
    if (lane == 0) {
        const float bb = bias[j];
#pragma unroll
        for (int b = 0; b < NBATCH; b++) out[(size_t)b * DM + j] = acc[b] + bb;
    }
}

template<int K>
__global__ void k_dot(const float* __restrict__ X, const float* __restrict__ W,
                      const float* __restrict__ bias, float* __restrict__ out) {
    const int lane = threadIdx.x & 63;
    const int wid  = threadIdx.x >> 6;
    const int j = blockIdx.x * 4 + wid;
    const f32x4* Wr = (const f32x4*)(W + (size_t)j * K);
    float acc[NBATCH] = {0.f, 0.f, 0.f, 0.f};
    constexpr int C = K / 4 / 64;
#pragma unroll
    for (int i = 0; i < C; i++) {
        f32x4 wv = Wr[lane + 64 * i];
#pragma unroll
        for (int b = 0; b < NBATCH; b++) {
            f32x4 xv = ((const f32x4*)(X + (size_t)b * K))[lane + 64 * i];
            acc[b] += wv[0]*xv[0] + wv[1]*xv[1] + wv[2]*xv[2] + wv[3]*xv[3];
        }
    }
#pragma unroll
    for (int off = 32; off; off >>= 1)
#pragma unroll
        for (int b = 0; b < NBATCH; b++) acc[b] += __shfl_down(acc[b], off);
    if (lane == 0) {
        const float bb = bias[j];
#pragma unroll
        for (int b = 0; b < NBATCH; b++) out[(size_t)b * DM + j] = acc[b] + bb;
    }
}

__global__ void k_ln_small(const float* __restrict__ in, const float* __restrict__ g,
                           const float* __restrict__ bt, float* __restrict__ out) {
    const int row = blockIdx.x;
    const int tid = threadIdx.x;
    const f32x4* ir = (const f32x4*)(in + (size_t)row * DM);
    f32x4 v0 = ir[tid], v1 = ir[tid + 256];
    float s  = v0[0]+v0[1]+v0[2]+v0[3] + v1[0]+v1[1]+v1[2]+v1[3];
    float s2 = v0[0]*v0[0]+v0[1]*v0[1]+v0[2]*v0[2]+v0[3]*v0[3]
             + v1[0]*v1[0]+v1[1]*v1[1]+v1[2]*v1[2]+v1[3]*v1[3];
    block_reduce_2(s, s2);
    const float mu = s * (1.0f / DM);
    const float r  = rsqrtf(s2 * (1.0f / DM) - mu * mu + LN_EPS);
    f32x4 g0 = ((const f32x4*)g)[tid],  g1v = ((const f32x4*)g)[tid + 256];
    f32x4 b0 = ((const f32x4*)bt)[tid], b1v = ((const f32x4*)bt)[tid + 256];
    f32x4 o0 = (v0 - mu) * r * g0 + b0;
    f32x4 o1 = (v1 - mu) * r * g1v + b1v;
    f32x4* orow = (f32x4*)(out + (size_t)row * DM);
    orow[tid] = o0; orow[tid + 256] = o1;
}

__global__ void k_stats_pack(const float* __restrict__ h, const float* __restrict__ attnv,
                             const float* __restrict__ g2, const float* __restrict__ b2,
                             int8_t* __restrict__ Aq,
                             float* __restrict__ muA, float* __restrict__ rA) {
    const int m = blockIdx.x;
    const int b = m >> 12;
    const int tid = threadIdx.x;
    const f32x4* hr = (const f32x4*)(h + (size_t)m * DM);
    const f32x4* ar = (const f32x4*)(attnv + (size_t)b * DM);
    f32x4 h0 = hr[2*tid], h1 = hr[2*tid + 1];
    f32x4 a0 = ar[2*tid], a1 = ar[2*tid + 1];
    f32x4 x0 = h0 + a0, x1 = h1 + a1;
    float s  = x0[0]+x0[1]+x0[2]+x0[3] + x1[0]+x1[1]+x1[2]+x1[3];
    float s2 = x0[0]*x0[0]+x0[1]*x0[1]+x0[2]*x0[2]+x0[3]*x0[3]
             + x1[0]*x1[0]+x1[1]*x1[1]+x1[2]*x1[2]+x1[3]*x1[3];
    block_reduce_2(s, s2);
    const float mu = s * (1.0f / DM);
    const float r  = rsqrtf(s2 * (1.0f / DM) - mu * mu + LN_EPS);
    if (tid == 0) { muA[m] = mu; rA[m] = r; }
    f32x4 gg0 = ((const f32x4*)g2)[2*tid], gg1 = ((const f32x4*)g2)[2*tid + 1];
    f32x4 bb0 = ((const f32x4*)b2)[2*tid], bb1 = ((const f32x4*)b2)[2*tid + 1];
    f32x4 ao0 = (x0 - mu) * r * gg0 + bb0;
    f32x4 ao1 = (x1 - mu) * r * gg1 + bb1;
    i8x8 qh, qa;
#pragma unroll
    for (int q = 0; q < 4; q++) {
        qh[q] = q8(h0[q], SCL_A);  qh[4+q] = q8(h1[q], SCL_A);
        qa[q] = q8(ao0[q], SCL_A); qa[4+q] = q8(ao1[q], SCL_A);
    }
    *(i8x8*)(Aq + (size_t)m * KC + 8*tid) = qh;
    *(i8x8*)(Aq + (size_t)m * KC + DM + 8*tid) = qa;
}

// ---------- 256x256 i8 GEMM v13: BK=128 single 64KB buffer, launch_bounds(512,2) ----------
// r13 retry with the spill bug fixed: (512,2) keeps VGPR=128 (r7-proven); occupancy 2
// blocks/CU comes NATURALLY from LDS=64KB + VGPR=128 (never force it via launch_bounds —
// r13's (512,4) capped VGPR at 64 and spilled acc to scratch: 5.8GB HBM traffic).
// Two co-resident blocks run anti-phased; block B's MFMA covers block A's stage drain.
#define MF(a,b,c) __builtin_amdgcn_mfma_i32_16x16x64_i8(a,b,c,0,0,0)
#define SCHED0() __builtin_amdgcn_sched_barrier(0)
#define BAR()  { SCHED0(); asm volatile("s_barrier" ::: "memory"); SCHED0(); }
#define VM(n)  { asm volatile("s_waitcnt vmcnt(" #n ")" ::: "memory"); SCHED0(); }
#define LGKM(n) { asm volatile("s_waitcnt lgkmcnt(" #n ")" ::: "memory"); SCHED0(); }

__global__ __launch_bounds__(512, 2) void k_gemm256(const int8_t* __restrict__ A, const int8_t* __restrict__ Bw,
                                                    const float* __restrict__ bgate, uint8_t* __restrict__ gq) {
    __shared__ __align__(128) char smem[65536];   // single buf: [A 32KB | B 32KB]
    const int tid  = threadIdx.x;
    const int lane = tid & 63;
    const int wid  = tid >> 6;
    const int wm   = wid >> 2, wn = wid & 3;

    // bijective XCD swizzle: 512 blocks, 8 XCDs
    const int swz = (blockIdx.x & 7) * 64 + (blockIdx.x >> 3);
    const int bm = (swz >> 3) << 8;
    const int bn = (swz & 7) << 8;

    // staging: inverse-swizzled global source (r7 scheme), linear LDS dest
    const int r_local = tid >> 3;                 // row within a 64-row round
    const int sc = (tid & 7) ^ (r_local & 7);     // swizzled 16B chunk in 128B row
    const int8_t* Abase = A  + (size_t)(bm + r_local) * KC + sc*16;
    const int8_t* Bbase = Bw + (size_t)(bn + r_local) * KC + sc*16;
    const int ldsW = wid << 10;

#define STAGEA(rnd, kt) __builtin_amdgcn_global_load_lds( \
        (const AS1 void*)(Abase + (size_t)(rnd)*64*KC + (kt)*128), \
        (AS3 void*)(smem + (rnd)*8192 + ldsW), 16, 0, 0)
#define STAGEB(rnd, kt) __builtin_amdgcn_global_load_lds( \
        (const AS1 void*)(Bbase + (size_t)(rnd)*64*KC + (kt)*128), \
        (AS3 void*)(smem + 32768 + (rnd)*8192 + ldsW), 16, 0, 0)

    // fragment read byte offsets (r7 swizzle); rows are 128B
    const int co0 = ((lane >> 4) ^ (lane & 7)) << 4;         // ks=0: chunks 0-3
    const int co1 = ((4 + (lane >> 4)) ^ (lane & 7)) << 4;   // ks=1: chunks 4-7
    const int arowb = (wm*128 + (lane & 15)) * 128;
    const int browb = (wn*64  + (lane & 15)) * 128;

#define AFRG(m, ks) (*(const i32x4*)(smem + arowb + (m)*2048 + ((ks) ? co1 : co0)))
#define BFRG(n, ks) (*(const i32x4*)(smem + 32768 + browb + (n)*2048 + ((ks) ? co1 : co0)))

    i32x4 acc[8][4] = {};
    i32x4 aLo[4][2], aHi[4][2], b01[2][2], b23[2][2];

#define LOAD_ALO() { _Pragma("unroll") for (int i = 0; i < 4; i++) { aLo[i][0] = AFRG(i,0);   aLo[i][1] = AFRG(i,1);   } }
#define LOAD_AHI() { _Pragma("unroll") for (int i = 0; i < 4; i++) { aHi[i][0] = AFRG(4+i,0); aHi[i][1] = AFRG(4+i,1); } }
#define LOAD_B01() { _Pragma("unroll") for (int j = 0; j < 2; j++) { b01[j][0] = BFRG(j,0);   b01[j][1] = BFRG(j,1);   } }
#define LOAD_B23() { _Pragma("unroll") for (int j = 0; j < 2; j++) { b23[j][0] = BFRG(2+j,0); b23[j][1] = BFRG(2+j,1); } }

#define MMQ(MOFF, AF, BF, NOFF) { _Pragma("unroll") for (int i = 0; i < 4; i++) \
        _Pragma("unroll") for (int j = 0; j < 2; j++) { \
            acc[(MOFF)+i][(NOFF)+j] = MF(AF[i][0], BF[j][0], acc[(MOFF)+i][(NOFF)+j]); \
            acc[(MOFF)+i][(NOFF)+j] = MF(AF[i][1], BF[j][1], acc[(MOFF)+i][(NOFF)+j]); } }

    for (int T = 0; T < NTILES; ++T) {
        // stage tile T (buffer free: all waves passed the end-BAR of T-1)
        STAGEB(0, T); STAGEB(1, T); STAGEB(2, T); STAGEB(3, T);
        STAGEA(0, T); STAGEA(1, T); STAGEA(2, T); STAGEA(3, T);
        VM(0);
        BAR();
        // compute (r7 ladder): 16 reads, LGKM(4), Q0; 8 reads ahead, LGKM(8), Q1; LGKM(0) Q2; Q3
        LOAD_ALO(); LOAD_B01(); LOAD_B23(); SCHED0();
        LGKM(4);
        __builtin_amdgcn_s_setprio(1);
        MMQ(0, aLo, b01, 0);
        __builtin_amdgcn_s_setprio(0); SCHED0();
        LOAD_AHI(); SCHED0();
        LGKM(8);
        __builtin_amdgcn_s_setprio(1);
        MMQ(0, aLo, b23, 2);
        __builtin_amdgcn_s_setprio(0); SCHED0();
        LGKM(0);
        __builtin_amdgcn_s_setprio(1);
        MMQ(4, aHi, b23, 2);
        __builtin_amdgcn_s_setprio(0); SCHED0();
        __builtin_amdgcn_s_setprio(1);
        MMQ(4, aHi, b01, 0);
        __builtin_amdgcn_s_setprio(0); SCHED0();
        BAR();   // all waves done reading tile T -> safe to overwrite
    }

    // ---- epilogue: gate = sigmoid(acc*DESCALE + bias) -> u8
#pragma unroll
    for (int n = 0; n < 4; n++) {
        const int col = bn + wn*64 + n*16 + (lane & 15);
        const float bg = bgate[col];
#pragma unroll
        for (int m = 0; m < 8; m++) {
            const int row = bm + wm*128 + m*16 + ((lane >> 4) << 2);
#pragma unroll
            for (int r = 0; r < 4; r++) {
                const float z = (float)acc[m][n][r] * DESCALE + bg;
                const float gate = 1.0f / (1.0f + __expf(-z));
                gq[(size_t)(row + r) * DM + col] = (uint8_t)(int)rintf(gate * 255.0f);
            }
        }
    }
}

// ---------- epilogue: blend with u8 gate + i8 h (from Aq), LN3 per row ----------
__global__ void k_epilogue(const int8_t* __restrict__ Aq, const uint8_t* __restrict__ gq,
                           const float* __restrict__ attnv, const float* __restrict__ muA,
                           const float* __restrict__ rA,
                           const float* __restrict__ g2, const float* __restrict__ b2,
                           const float* __restrict__ g3, const float* __restrict__ b3,
                           float* __restrict__ out) {
    const int m = blockIdx.x;
    const int b = m >> 12;
    const int tid = threadIdx.x;
    i8x8 qh = *(const i8x8*)(Aq + (size_t)m * KC + 8*tid);
    f32x4 h0, h1;
#pragma unroll
    for (int q = 0; q < 4; q++) { h0[q] = (float)qh[q] * INV_SCL_A; h1[q] = (float)qh[4+q] * INV_SCL_A; }
    const f32x4* ar = (const f32x4*)(attnv + (size_t)b * DM);
    f32x4 a0 = ar[2*tid], a1 = ar[2*tid + 1];
    const float mu = muA[m];
    const float r  = rA[m];
    f32x4 gg0 = ((const f32x4*)g2)[2*tid], gg1 = ((const f32x4*)g2)[2*tid + 1];
    f32x4 bb0 = ((const f32x4*)b2)[2*tid], bb1 = ((const f32x4*)b2)[2*tid + 1];
    f32x4 ao0 = (h0 + a0 - mu) * r * gg0 + bb0;
    f32x4 ao1 = (h1 + a1 - mu) * r * gg1 + bb1;
    u8x8 qv = *(const u8x8*)(gq + (size_t)m * DM + 8*tid);
    f32x4 gt0, gt1;
#pragma unroll
    for (int q = 0; q < 4; q++) {
        gt0[q] = (float)qv[q]   * (1.0f / 255.0f);
        gt1[q] = (float)qv[4+q] * (1.0f / 255.0f);
    }
    f32x4 f0 = h0 + gt0 * (ao0 - h0);
    f32x4 f1 = h1 + gt1 * (ao1 - h1);
    float s  = f0[0]+f0[1]+f0[2]+f0[3] + f1[0]+f1[1]+f1[2]+f1[3];
    float s2 = f0[0]*f0[0]+f0[1]*f0[1]+f0[2]*f0[2]+f0[3]*f0[3]
             + f1[0]*f1[0]+f1[1]*f1[1]+f1[2]*f1[2]+f1[3]*f1[3];
    block_reduce_2(s, s2);
    const float mu3 = s * (1.0f / DM);
    const float r3  = rsqrtf(s2 * (1.0f / DM) - mu3 * mu3 + LN_EPS);
    f32x4 g30 = ((const f32x4*)g3)[2*tid], g31 = ((const f32x4*)g3)[2*tid + 1];
    f32x4 b30 = ((const f32x4*)b3)[2*tid], b31 = ((const f32x4*)b3)[2*tid + 1];
    f32x4 o0 = (f0 - mu3) * r3 * g30 + b30;
    f32x4 o1 = (f1 - mu3) * r3 * g31 + b31;
    f32x4* orow = (f32x4*)(out + (size_t)m * DM);
    orow[2*tid] = o0; orow[2*tid + 1] = o1;
}

extern "C" void kernel_launch(void* const* d_in, const int* in_sizes, int n_in,
                              void* d_out, int out_size, void* d_ws, size_t ws_size,
                              hipStream_t stream) {
    const float* h_llm    = (const float*)d_in[0];
    const float* h_change = (const float*)d_in[1];
    const float* w_proj   = (const float*)d_in[2];
    const float* b_proj   = (const float*)d_in[3];
    const float* g1       = (const float*)d_in[4];
    const float* b1       = (const float*)d_in[5];
    const float* w_v      = (const float*)d_in[6];
    const float* b_v      = (const float*)d_in[7];
    const float* w_o      = (const float*)d_in[8];
    const float* b_o      = (const float*)d_in[9];
    const float* g2       = (const float*)d_in[10];
    const float* b2       = (const float*)d_in[11];
    const float* w_gate   = (const float*)d_in[12];
    const float* b_gate   = (const float*)d_in[13];
    const float* g3       = (const float*)d_in[14];
    const float* b3       = (const float*)d_in[15];
    float* out = (float*)d_out;

    char* ws = (char*)d_ws;
    int8_t* Aq  = (int8_t*)ws; ws += (size_t)NM * KC;          // 67.1 MB
    int8_t* wqb = (int8_t*)ws; ws += (size_t)DM * KC;          // 8.4 MB
    uint8_t* gq = (uint8_t*)ws; ws += (size_t)NM * DM;         // 33.5 MB
    float* muA = (float*)ws;  ws += (size_t)NM * 4;
    float* rA  = (float*)ws;  ws += (size_t)NM * 4;
    float* raw1 = (float*)ws; ws += (size_t)NBATCH * DM * 4;
    float* hc   = (float*)ws; ws += (size_t)NBATCH * DM * 4;
    float* raw2 = (float*)ws; ws += (size_t)NBATCH * DM * 4;
    float* attnv= (float*)ws; ws += (size_t)NBATCH * DM * 4;

    k_pack_dot1<<<4608, 256, 0, stream>>>(w_gate, wqb, h_change, w_proj, b_proj, raw1);
    k_ln_small<<<NBATCH, 256, 0, stream>>>(raw1, g1, b1, hc);
    k_dot<DM><<<DM / 4, 256, 0, stream>>>(hc, w_v, b_v, raw2);
    k_dot<DM><<<DM / 4, 256, 0, stream>>>(raw2, w_o, b_o, attnv);
    k_stats_pack<<<NM, 256, 0, stream>>>(h_llm, attnv, g2, b2, Aq, muA, rA);
    k_gemm256<<<512, 512, 0, stream>>>(Aq, wqb, b_gate, gq);
    k_epilogue<<<NM, 256, 0, stream>>>(Aq, gq, attnv, muA, rA, g2, b2, g3, b3, out);
}

// Round 15
// 237.066 us; speedup vs baseline: 5.4843x; 1.1416x over previous
//
#include <hip/hip_runtime.h>
#include <hip/hip_bf16.h>
#include <cstdint>
#include <cstddef>

#define DM 2048
#define DG 512
#define NBATCH 4
#define NT 4096
#define NM (NBATCH*NT)     // 16384 rows
#define KC (2*DM)          // 4096 concat-K (i8 elems = bytes)
#define LN_EPS 1e-5f
#define NTILES (KC/128)    // 32 K-tiles of BK=128 i8
#define SCL_A 16.0f
#define SCL_B 8192.0f
#define DESCALE (1.0f/131072.0f)
#define INV_SCL_A 0.0625f

typedef __bf16 bf16;
typedef bf16 bf16x8 __attribute__((ext_vector_type(8)));
typedef float f32x4 __attribute__((ext_vector_type(4)));
typedef int   i32x4 __attribute__((ext_vector_type(4)));
typedef char  i8x8  __attribute__((ext_vector_type(8)));
typedef unsigned char u8x8 __attribute__((ext_vector_type(8)));

#define AS1 __attribute__((address_space(1)))
#define AS3 __attribute__((address_space(3)))

__device__ __forceinline__ char q8(float x, float s) {
    int v = (int)rintf(x * s);
    v = v > 127 ? 127 : (v < -127 ? -127 : v);
    return (char)v;
}

__device__ __forceinline__ void block_reduce_2(float& s, float& s2) {
#pragma unroll
    for (int off = 32; off; off >>= 1) {
        s  += __shfl_down(s, off);
        s2 += __shfl_down(s2, off);
    }
    __shared__ float sm[8];
    const int wid = threadIdx.x >> 6, lane = threadIdx.x & 63;
    if (lane == 0) { sm[wid] = s; sm[4 + wid] = s2; }
    __syncthreads();
    s  = sm[0] + sm[1] + sm[2] + sm[3];
    s2 = sm[4] + sm[5] + sm[6] + sm[7];
}

// ---------- fused: blocks [0,512) = GEMV proj; blocks [512,4608) = w_gate->i8 ----------
__global__ void k_pack_dot1(const float* __restrict__ wg, int8_t* __restrict__ wqb,
                            const float* __restrict__ X, const float* __restrict__ W,
                            const float* __restrict__ bias, float* __restrict__ out) {
    if (blockIdx.x >= 512) {
        const int i = (blockIdx.x - 512) * 256 + threadIdx.x;
        const f32x4* s = (const f32x4*)wg + (size_t)i * 2;
        f32x4 a = s[0], b = s[1];
        i8x8 o;
#pragma unroll
        for (int q = 0; q < 4; q++) { o[q] = q8(a[q], SCL_B); o[4+q] = q8(b[q], SCL_B); }
        *((i8x8*)wqb + i) = o;
        return;
    }
    const int lane = threadIdx.x & 63;
    const int wid  = threadIdx.x >> 6;
    const int j = blockIdx.x * 4 + wid;
    const f32x4* Wr = (const f32x4*)(W + (size_t)j * DG);
    float acc[NBATCH] = {0.f, 0.f, 0.f, 0.f};
    constexpr int C = DG / 4 / 64;
#pragma unroll
    for (int i = 0; i < C; i++) {
        f32x4 wv = Wr[lane + 64 * i];
#pragma unroll
        for (int b = 0; b < NBATCH; b++) {
            f32x4 xv = ((const f32x4*)(X + (size_t)b * DG))[lane + 64 * i];
            acc[b] += wv[0]*xv[0] + wv[1]*xv[1] + wv[2]*xv[2] + wv[3]*xv[3];
        }
    }
#pragma unroll
    for (int off = 32; off; off >>= 1)
#pragma unroll
        for (int b = 0; b < NBATCH; b++) acc[b] += __shfl_down(acc[b], off);
    if (lane == 0) {
        const float bb = bias[j];
#pragma unroll
        for (int b = 0; b < NBATCH; b++) out[(size_t)b * DM + j] = acc[b] + bb;
    }
}

template<int K>
__global__ void k_dot(const float* __restrict__ X, const float* __restrict__ W,
                      const float* __restrict__ bias, float* __restrict__ out) {
    const int lane = threadIdx.x & 63;
    const int wid  = threadIdx.x >> 6;
    const int j = blockIdx.x * 4 + wid;
    const f32x4* Wr = (const f32x4*)(W + (size_t)j * K);
    float acc[NBATCH] = {0.f, 0.f, 0.f, 0.f};
    constexpr int C = K / 4 / 64;
#pragma unroll
    for (int i = 0; i < C; i++) {
        f32x4 wv = Wr[lane + 64 * i];
#pragma unroll
        for (int b = 0; b < NBATCH; b++) {
            f32x4 xv = ((const f32x4*)(X + (size_t)b * K))[lane + 64 * i];
            acc[b] += wv[0]*xv[0] + wv[1]*xv[1] + wv[2]*xv[2] + wv[3]*xv[3];
        }
    }
#pragma unroll
    for (int off = 32; off; off >>= 1)
#pragma unroll
        for (int b = 0; b < NBATCH; b++) acc[b] += __shfl_down(acc[b], off);
    if (lane == 0) {
        const float bb = bias[j];
#pragma unroll
        for (int b = 0; b < NBATCH; b++) out[(size_t)b * DM + j] = acc[b] + bb;
    }
}

__global__ void k_ln_small(const float* __restrict__ in, const float* __restrict__ g,
                           const float* __restrict__ bt, float* __restrict__ out) {
    const int row = blockIdx.x;
    const int tid = threadIdx.x;
    const f32x4* ir = (const f32x4*)(in + (size_t)row * DM);
    f32x4 v0 = ir[tid], v1 = ir[tid + 256];
    float s  = v0[0]+v0[1]+v0[2]+v0[3] + v1[0]+v1[1]+v1[2]+v1[3];
    float s2 = v0[0]*v0[0]+v0[1]*v0[1]+v0[2]*v0[2]+v0[3]*v0[3]
             + v1[0]*v1[0]+v1[1]*v1[1]+v1[2]*v1[2]+v1[3]*v1[3];
    block_reduce_2(s, s2);
    const float mu = s * (1.0f / DM);
    const float r  = rsqrtf(s2 * (1.0f / DM) - mu * mu + LN_EPS);
    f32x4 g0 = ((const f32x4*)g)[tid],  g1v = ((const f32x4*)g)[tid + 256];
    f32x4 b0 = ((const f32x4*)bt)[tid], b1v = ((const f32x4*)bt)[tid + 256];
    f32x4 o0 = (v0 - mu) * r * g0 + b0;
    f32x4 o1 = (v1 - mu) * r * g1v + b1v;
    f32x4* orow = (f32x4*)(out + (size_t)row * DM);
    orow[tid] = o0; orow[tid + 256] = o1;
}

__global__ void k_stats_pack(const float* __restrict__ h, const float* __restrict__ attnv,
                             const float* __restrict__ g2, const float* __restrict__ b2,
                             int8_t* __restrict__ Aq,
                             float* __restrict__ muA, float* __restrict__ rA) {
    const int m = blockIdx.x;
    const int b = m >> 12;
    const int tid = threadIdx.x;
    const f32x4* hr = (const f32x4*)(h + (size_t)m * DM);
    const f32x4* ar = (const f32x4*)(attnv + (size_t)b * DM);
    f32x4 h0 = hr[2*tid], h1 = hr[2*tid + 1];
    f32x4 a0 = ar[2*tid], a1 = ar[2*tid + 1];
    f32x4 x0 = h0 + a0, x1 = h1 + a1;
    float s  = x0[0]+x0[1]+x0[2]+x0[3] + x1[0]+x1[1]+x1[2]+x1[3];
    float s2 = x0[0]*x0[0]+x0[1]*x0[1]+x0[2]*x0[2]+x0[3]*x0[3]
             + x1[0]*x1[0]+x1[1]*x1[1]+x1[2]*x1[2]+x1[3]*x1[3];
    block_reduce_2(s, s2);
    const float mu = s * (1.0f / DM);
    const float r  = rsqrtf(s2 * (1.0f / DM) - mu * mu + LN_EPS);
    if (tid == 0) { muA[m] = mu; rA[m] = r; }
    f32x4 gg0 = ((const f32x4*)g2)[2*tid], gg1 = ((const f32x4*)g2)[2*tid + 1];
    f32x4 bb0 = ((const f32x4*)b2)[2*tid], bb1 = ((const f32x4*)b2)[2*tid + 1];
    f32x4 ao0 = (x0 - mu) * r * gg0 + bb0;
    f32x4 ao1 = (x1 - mu) * r * gg1 + bb1;
    i8x8 qh, qa;
#pragma unroll
    for (int q = 0; q < 4; q++) {
        qh[q] = q8(h0[q], SCL_A);  qh[4+q] = q8(h1[q], SCL_A);
        qa[q] = q8(ao0[q], SCL_A); qa[4+q] = q8(ao1[q], SCL_A);
    }
    *(i8x8*)(Aq + (size_t)m * KC + 8*tid) = qh;
    *(i8x8*)(Aq + (size_t)m * KC + DM + 8*tid) = qa;
}

// ---------- 256x256 i8 MFMA GEMM (r7/r9 best-measured: 129us, MfmaUtil 48, 0 conflicts) ----------
// BK=128, double-buffered 128KB LDS, 1 barrier/tile, free VM(0), lgkm-ahead read ladder.
// Structural limit of this family (r8-r14 experiments): 8 waves/CU is register-bound
// (acc 128 AGPR + 124 VGPR per wave), so no second block can cover the LDS<->MFMA
// serialization within the barrier-locked block. Do not force occupancy via
// launch_bounds (r13: (512,4) spilled acc to scratch, 9x slowdown).
#define MF(a,b,c) __builtin_amdgcn_mfma_i32_16x16x64_i8(a,b,c,0,0,0)
#define SCHED0() __builtin_amdgcn_sched_barrier(0)
#define BAR()  { SCHED0(); asm volatile("s_barrier" ::: "memory"); SCHED0(); }
#define VM(n)  { asm volatile("s_waitcnt vmcnt(" #n ")" ::: "memory"); SCHED0(); }
#define LGKM(n) { asm volatile("s_waitcnt lgkmcnt(" #n ")" ::: "memory"); SCHED0(); }

__global__ __launch_bounds__(512, 2) void k_gemm256(const int8_t* __restrict__ A, const int8_t* __restrict__ Bw,
                                                    const float* __restrict__ bgate, uint8_t* __restrict__ gq) {
    __shared__ __align__(128) char smem[131072];   // [2 bufs][A 32KB | B 32KB]
    const int tid  = threadIdx.x;
    const int lane = tid & 63;
    const int wid  = tid >> 6;
    const int wm   = wid >> 2, wn = wid & 3;

    // bijective XCD swizzle: 512 blocks, 8 XCDs
    const int swz = (blockIdx.x & 7) * 64 + (blockIdx.x >> 3);
    const int bm = (swz >> 3) << 8;
    const int bn = (swz & 7) << 8;

    // staging: inverse-swizzled global source (bytes), linear LDS dest
    const int r_local = tid >> 3;                 // row within a 64-row round
    const int sc = (tid & 7) ^ (r_local & 7);     // swizzled 16B chunk
    const int8_t* Abase = A  + (size_t)(bm + r_local) * KC + sc*16;
    const int8_t* Bbase = Bw + (size_t)(bn + r_local) * KC + sc*16;
    const int ldsW = wid << 10;

#define STAGEA(buf, rnd, kt) __builtin_amdgcn_global_load_lds( \
        (const AS1 void*)(Abase + (size_t)(rnd)*64*KC + (kt)*128), \
        (AS3 void*)(smem + (buf)*65536 + (rnd)*8192 + ldsW), 16, 0, 0)
#define STAGEB(buf, rnd, kt) __builtin_amdgcn_global_load_lds( \
        (const AS1 void*)(Bbase + (size_t)(rnd)*64*KC + (kt)*128), \
        (AS3 void*)(smem + (buf)*65536 + 32768 + (rnd)*8192 + ldsW), 16, 0, 0)

    // fragment read byte offsets (swizzled); rows are 128B
    const int co0 = ((lane >> 4) ^ (lane & 7)) << 4;         // ks=0: chunks 0-3
    const int co1 = ((4 + (lane >> 4)) ^ (lane & 7)) << 4;   // ks=1: chunks 4-7
    const int arowb = (wm*128 + (lane & 15)) * 128;
    const int browb = (wn*64  + (lane & 15)) * 128;

#define AFRG(buf, m, ks) (*(const i32x4*)(smem + (buf)*65536 + arowb + (m)*2048 + ((ks) ? co1 : co0)))
#define BFRG(buf, n, ks) (*(const i32x4*)(smem + (buf)*65536 + 32768 + browb + (n)*2048 + ((ks) ? co1 : co0)))

    i32x4 acc[8][4] = {};
    i32x4 aLo[4][2], aHi[4][2], b01[2][2], b23[2][2];

#define LOAD_ALO(buf) { _Pragma("unroll") for (int i = 0; i < 4; i++) { aLo[i][0] = AFRG(buf,i,0);   aLo[i][1] = AFRG(buf,i,1);   } }
#define LOAD_AHI(buf) { _Pragma("unroll") for (int i = 0; i < 4; i++) { aHi[i][0] = AFRG(buf,4+i,0); aHi[i][1] = AFRG(buf,4+i,1); } }
#define LOAD_B01(buf) { _Pragma("unroll") for (int j = 0; j < 2; j++) { b01[j][0] = BFRG(buf,j,0);   b01[j][1] = BFRG(buf,j,1);   } }
#define LOAD_B23(buf) { _Pragma("unroll") for (int j = 0; j < 2; j++) { b23[j][0] = BFRG(buf,2+j,0); b23[j][1] = BFRG(buf,2+j,1); } }

#define MMQ(MOFF, AF, BF, NOFF) { _Pragma("unroll") for (int i = 0; i < 4; i++) \
        _Pragma("unroll") for (int j = 0; j < 2; j++) { \
            acc[(MOFF)+i][(NOFF)+j] = MF(AF[i][0], BF[j][0], acc[(MOFF)+i][(NOFF)+j]); \
            acc[(MOFF)+i][(NOFF)+j] = MF(AF[i][1], BF[j][1], acc[(MOFF)+i][(NOFF)+j]); } }

    // ---- prologue: tile 0 -> buf0, full drain once
    STAGEB(0,0,0); STAGEB(0,1,0); STAGEB(0,2,0); STAGEB(0,3,0);
    STAGEA(0,0,0); STAGEA(0,2,0); STAGEA(0,1,0); STAGEA(0,3,0);
    VM(0);
    BAR();

#define TILE_BODY(TT, BUF, NBUF) { \
    const bool g = (TT) < NTILES - 1; \
    /* P0: stage B0-3(T+1); issue 16 reads (aLo,b01 + b23 ahead); Q0 */ \
    if (g) { STAGEB(NBUF,0,(TT)+1); STAGEB(NBUF,1,(TT)+1); STAGEB(NBUF,2,(TT)+1); STAGEB(NBUF,3,(TT)+1); } \
    LOAD_ALO(BUF); LOAD_B01(BUF); LOAD_B23(BUF); SCHED0(); \
    LGKM(4); \
    __builtin_amdgcn_s_setprio(1); \
    MMQ(0, aLo, b01, 0); \
    __builtin_amdgcn_s_setprio(0); SCHED0(); \
    /* P1: stage A0-3(T+1); issue aHi ahead; Q1 */ \
    if (g) { STAGEA(NBUF,0,(TT)+1); STAGEA(NBUF,1,(TT)+1); STAGEA(NBUF,2,(TT)+1); STAGEA(NBUF,3,(TT)+1); } \
    LOAD_AHI(BUF); SCHED0(); \
    LGKM(8); \
    __builtin_amdgcn_s_setprio(1); \
    MMQ(0, aLo, b23, 2); \
    __builtin_amdgcn_s_setprio(0); SCHED0(); \
    /* P2: Q2 (aHi drained under Q1) */ \
    LGKM(0); \
    __builtin_amdgcn_s_setprio(1); \
    MMQ(4, aHi, b23, 2); \
    __builtin_amdgcn_s_setprio(0); SCHED0(); \
    /* P3: Q3 (b01 still live); free VM(0) (stages landed under Q1-Q3); BAR */ \
    __builtin_amdgcn_s_setprio(1); \
    MMQ(4, aHi, b01, 0); \
    __builtin_amdgcn_s_setprio(0); SCHED0(); \
    VM(0); \
    BAR(); \
}

    for (int T = 0; T < NTILES; T += 2) {
        TILE_BODY(T,   0, 1);
        TILE_BODY(T+1, 1, 0);
    }

    // ---- epilogue: gate = sigmoid(acc*DESCALE + bias) -> u8
#pragma unroll
    for (int n = 0; n < 4; n++) {
        const int col = bn + wn*64 + n*16 + (lane & 15);
        const float bg = bgate[col];
#pragma unroll
        for (int m = 0; m < 8; m++) {
            const int row = bm + wm*128 + m*16 + ((lane >> 4) << 2);
#pragma unroll
            for (int r = 0; r < 4; r++) {
                const float z = (float)acc[m][n][r] * DESCALE + bg;
                const float gate = 1.0f / (1.0f + __expf(-z));
                gq[(size_t)(row + r) * DM + col] = (uint8_t)(int)rintf(gate * 255.0f);
            }
        }
    }
}

// ---------- epilogue: blend with u8 gate + i8 h (from Aq), LN3 per row ----------
__global__ void k_epilogue(const int8_t* __restrict__ Aq, const uint8_t* __restrict__ gq,
                           const float* __restrict__ attnv, const float* __restrict__ muA,
                           const float* __restrict__ rA,
                           const float* __restrict__ g2, const float* __restrict__ b2,
                           const float* __restrict__ g3, const float* __restrict__ b3,
                           float* __restrict__ out) {
    const int m = blockIdx.x;
    const int b = m >> 12;
    const int tid = threadIdx.x;
    i8x8 qh = *(const i8x8*)(Aq + (size_t)m * KC + 8*tid);
    f32x4 h0, h1;
#pragma unroll
    for (int q = 0; q < 4; q++) { h0[q] = (float)qh[q] * INV_SCL_A; h1[q] = (float)qh[4+q] * INV_SCL_A; }
    const f32x4* ar = (const f32x4*)(attnv + (size_t)b * DM);
    f32x4 a0 = ar[2*tid], a1 = ar[2*tid + 1];
    const float mu = muA[m];
    const float r  = rA[m];
    f32x4 gg0 = ((const f32x4*)g2)[2*tid], gg1 = ((const f32x4*)g2)[2*tid + 1];
    f32x4 bb0 = ((const f32x4*)b2)[2*tid], bb1 = ((const f32x4*)b2)[2*tid + 1];
    f32x4 ao0 = (h0 + a0 - mu) * r * gg0 + bb0;
    f32x4 ao1 = (h1 + a1 - mu) * r * gg1 + bb1;
    u8x8 qv = *(const u8x8*)(gq + (size_t)m * DM + 8*tid);
    f32x4 gt0, gt1;
#pragma unroll
    for (int q = 0; q < 4; q++) {
        gt0[q] = (float)qv[q]   * (1.0f / 255.0f);
        gt1[q] = (float)qv[4+q] * (1.0f / 255.0f);
    }
    f32x4 f0 = h0 + gt0 * (ao0 - h0);
    f32x4 f1 = h1 + gt1 * (ao1 - h1);
    float s  = f0[0]+f0[1]+f0[2]+f0[3] + f1[0]+f1[1]+f1[2]+f1[3];
    float s2 = f0[0]*f0[0]+f0[1]*f0[1]+f0[2]*f0[2]+f0[3]*f0[3]
             + f1[0]*f1[0]+f1[1]*f1[1]+f1[2]*f1[2]+f1[3]*f1[3];
    block_reduce_2(s, s2);
    const float mu3 = s * (1.0f / DM);
    const float r3  = rsqrtf(s2 * (1.0f / DM) - mu3 * mu3 + LN_EPS);
    f32x4 g30 = ((const f32x4*)g3)[2*tid], g31 = ((const f32x4*)g3)[2*tid + 1];
    f32x4 b30 = ((const f32x4*)b3)[2*tid], b31 = ((const f32x4*)b3)[2*tid + 1];
    f32x4 o0 = (f0 - mu3) * r3 * g30 + b30;
    f32x4 o1 = (f1 - mu3) * r3 * g31 + b31;
    f32x4* orow = (f32x4*)(out + (size_t)m * DM);
    orow[2*tid] = o0; orow[2*tid + 1] = o1;
}

extern "C" void kernel_launch(void* const* d_in, const int* in_sizes, int n_in,
                              void* d_out, int out_size, void* d_ws, size_t ws_size,
                              hipStream_t stream) {
    const float* h_llm    = (const float*)d_in[0];
    const float* h_change = (const float*)d_in[1];
    const float* w_proj   = (const float*)d_in[2];
    const float* b_proj   = (const float*)d_in[3];
    const float* g1       = (const float*)d_in[4];
    const float* b1       = (const float*)d_in[5];
    const float* w_v      = (const float*)d_in[6];
    const float* b_v      = (const float*)d_in[7];
    const float* w_o      = (const float*)d_in[8];
    const float* b_o      = (const float*)d_in[9];
    const float* g2       = (const float*)d_in[10];
    const float* b2       = (const float*)d_in[11];
    const float* w_gate   = (const float*)d_in[12];
    const float* b_gate   = (const float*)d_in[13];
    const float* g3       = (const float*)d_in[14];
    const float* b3       = (const float*)d_in[15];
    float* out = (float*)d_out;

    char* ws = (char*)d_ws;
    int8_t* Aq  = (int8_t*)ws; ws += (size_t)NM * KC;          // 67.1 MB
    int8_t* wqb = (int8_t*)ws; ws += (size_t)DM * KC;          // 8.4 MB
    uint8_t* gq = (uint8_t*)ws; ws += (size_t)NM * DM;         // 33.5 MB
    float* muA = (float*)ws;  ws += (size_t)NM * 4;
    float* rA  = (float*)ws;  ws += (size_t)NM * 4;
    float* raw1 = (float*)ws; ws += (size_t)NBATCH * DM * 4;
    float* hc   = (float*)ws; ws += (size_t)NBATCH * DM * 4;
    float* raw2 = (float*)ws; ws += (size_t)NBATCH * DM * 4;
    float* attnv= (float*)ws; ws += (size_t)NBATCH * DM * 4;

    k_pack_dot1<<<4608, 256, 0, stream>>>(w_gate, wqb, h_change, w_proj, b_proj, raw1);
    k_ln_small<<<NBATCH, 256, 0, stream>>>(raw1, g1, b1, hc);
    k_dot<DM><<<DM / 4, 256, 0, stream>>>(hc, w_v, b_v, raw2);
    k_dot<DM><<<DM / 4, 256, 0, stream>>>(raw2, w_o, b_o, attnv);
    k_stats_pack<<<NM, 256, 0, stream>>>(h_llm, attnv, g2, b2, Aq, muA, rA);
    k_gemm256<<<512, 512, 0, stream>>>(Aq, wqb, b_gate, gq);
    k_epilogue<<<NM, 256, 0, stream>>>(Aq, gq, attnv, muA, rA, g2, b2, g3, b3, out);
}